// Round 10
// baseline (360.977 us; speedup 1.0000x reference)
//
#include <hip/hip_runtime.h>

// Static config (matches reference)
#define HP 24
#define WP 24
#define TF 9
#define HW (HP * WP)        // 576
#define DIM 768
#define D4 (DIM / 4)        // 192 groups of 4 elements per row
#define BATCH 4
#define NBOX 50
#define ROI_L (HP * WP)     // 576
#define NCHUNK (BATCH * NBOX * (ROI_L / 4))   // 28800 chunks of 4 rows
#define GRID 1024           // 4 blocks/CU x 256 CU -> guaranteed co-resident
#define MEAN_UNITS (BATCH * HW * D4)          // 442368 ushort4 units

typedef float v4f __attribute__((ext_vector_type(4)));

// fp32 -> bf16 round-to-nearest-even (no NaN inputs in this problem)
__device__ __forceinline__ unsigned short f2bf(float f) {
    unsigned u = __float_as_uint(f);
    unsigned rounding = 0x7FFFu + ((u >> 16) & 1u);
    return (unsigned short)((u + rounding) >> 16);
}

// Geometry — EXACT arithmetic of the R7 passing kernel.
__device__ __forceinline__ void box_geometry(float4 bb, int& row_start, int& col_start,
                                             int& area, int& wsafe) {
    float cx = bb.x, cy = bb.y, bw = bb.z, bh = bb.w;
    float bwp = bw * 1.2f;
    float bhp = bh * 1.2f;

    // astype(int32) truncates toward zero == C (int) cast
    int cs = max((int)((cx - bwp * 0.5f) * (float)WP), 0);
    int ce = min((int)((cx + bwp * 0.5f) * (float)WP), WP);
    int rs = max((int)((cy - bhp * 0.5f) * (float)HP), 0);
    int re = min((int)((cy + bhp * 0.5f) * (float)HP), HP);

    // (a+b)/2 then trunc; a,b >= 0 so >>1 is exact
    int col_mid = (cs + ce) >> 1;
    int row_mid = (rs + re) >> 1;
    // half_min = MIN_PATCHES/2 = 1
    cs = min(cs, max(col_mid - 1, 0));
    ce = max(ce, min(col_mid + 2, WP));
    rs = min(rs, max(row_mid - 1, 0));
    re = max(re, min(row_mid + 2, HP));

    int h = max(re - rs, 0);
    int w = max(ce - cs, 0);
    area = h * w;
    wsafe = max(w, 1);
    row_start = rs;
    col_start = cs;
}

// ---------------------------------------------------------------------------
// Persistent kernel, regular launch (1024 blocks = 4/CU, all co-resident):
//   A: all blocks grid-stride the temporal mean -> sp (bf16)
//   B: zero-fill all-invalid chunks + their mask (independent of A;
//      mixes with A's read tail, no kernel-launch drain between them)
//   -- hand-rolled grid barrier (release fence + agent-scope atomics) --
//   C: gather chunks with valid rows from sp
// Each output row written exactly once. out_feat NT stores; sp reads cached.
// ---------------------------------------------------------------------------
__global__ void __launch_bounds__(192, 3)
fused_roi_kernel(const float* __restrict__ spatial, const float* __restrict__ bboxes,
                 ushort4* __restrict__ sp, unsigned* barrier_cnt,
                 unsigned* barrier_flag, float* __restrict__ out_feat,
                 float* __restrict__ out_mask) {
    int bid = blockIdx.x;
    int tid = threadIdx.x;          // 0..191
    v4f* outf4 = (v4f*)out_feat;

    // ---- Phase A: temporal mean (all blocks, grid-stride) ----
    for (int u = bid * 192 + tid; u < MEAN_UNITS; u += GRID * 192) {
        int d4 = u % D4;
        int hw = (u / D4) % HW;
        int b  = u / (D4 * HW);
        const float4* src =
            (const float4*)spatial + (size_t)((b * HW + hw) * TF) * D4 + d4;
        float4 acc = make_float4(0.f, 0.f, 0.f, 0.f);
#pragma unroll
        for (int t = 0; t < TF; ++t) {
            float4 v = src[(size_t)t * D4];
            acc.x += v.x; acc.y += v.y; acc.z += v.z; acc.w += v.w;
        }
        acc.x /= 9.0f; acc.y /= 9.0f; acc.z /= 9.0f; acc.w /= 9.0f;
        ushort4 o;
        o.x = f2bf(acc.x); o.y = f2bf(acc.y); o.z = f2bf(acc.z); o.w = f2bf(acc.w);
        sp[u] = o;
    }

    // ---- Phase B: all-invalid chunks (no sp dependency) ----
    for (int vb = bid; vb < NCHUNK; vb += GRID) {
        int ln = vb % (ROI_L / 4);
        int rest = vb / (ROI_L / 4);
        int n = rest % NBOX;
        int b = rest / NBOX;
        float4 bb = ((const float4*)bboxes)[b * NBOX + n];
        int row_start, col_start, area, wsafe;
        box_geometry(bb, row_start, col_start, area, wsafe);
        int base_l = ln * 4;
        if (base_l >= area) {
            size_t out_base = (size_t)(b * NBOX + n) * ROI_L;
            v4f z = (v4f)(0.f);
#pragma unroll
            for (int s = 0; s < 4; ++s) {
                __builtin_nontemporal_store(z, &outf4[(out_base + base_l + s) * D4 + tid]);
            }
            if (tid < 4) {
                out_mask[out_base + base_l + tid] = 1.0f;   // all padding
            }
        }
    }

    // ---- Grid barrier (counters zeroed by hipMemsetAsync each call) ----
    __threadfence();      // release: make this thread's sp stores device-visible
    __syncthreads();      // all threads in block have fenced
    if (tid == 0) {
        unsigned t = __hip_atomic_fetch_add(barrier_cnt, 1u, __ATOMIC_ACQ_REL,
                                            __HIP_MEMORY_SCOPE_AGENT);
        if (t == GRID - 1) {
            __hip_atomic_store(barrier_flag, 1u, __ATOMIC_RELEASE,
                               __HIP_MEMORY_SCOPE_AGENT);
        } else {
            while (__hip_atomic_load(barrier_flag, __ATOMIC_ACQUIRE,
                                     __HIP_MEMORY_SCOPE_AGENT) == 0u) {
                __builtin_amdgcn_s_sleep(8);
            }
        }
    }
    __syncthreads();
    __threadfence();      // acquire side: drop stale cached sp lines

    // ---- Phase C: chunks with valid rows (read sp) ----
    for (int vb = bid; vb < NCHUNK; vb += GRID) {
        int ln = vb % (ROI_L / 4);
        int rest = vb / (ROI_L / 4);
        int n = rest % NBOX;
        int b = rest / NBOX;
        float4 bb = ((const float4*)bboxes)[b * NBOX + n];
        int row_start, col_start, area, wsafe;
        box_geometry(bb, row_start, col_start, area, wsafe);
        int base_l = ln * 4;
        if (base_l < area) {
            size_t out_base = (size_t)(b * NBOX + n) * ROI_L;
#pragma unroll
            for (int s = 0; s < 4; ++s) {
                int l = base_l + s;
                v4f v = (v4f)(0.f);
                if (l < area) {
                    int r = row_start + l / wsafe;
                    int c = col_start + l % wsafe;
                    // valid => r,c in [0,23]; reference clip is a no-op here.
                    ushort4 u = sp[(size_t)(b * HW + r * WP + c) * D4 + tid];
                    // bf16 -> fp32 is an exact bit shift
                    v.x = __uint_as_float((unsigned)u.x << 16);
                    v.y = __uint_as_float((unsigned)u.y << 16);
                    v.z = __uint_as_float((unsigned)u.z << 16);
                    v.w = __uint_as_float((unsigned)u.w << 16);
                }
                __builtin_nontemporal_store(v, &outf4[(out_base + l) * D4 + tid]);
            }
            if (tid < 4) {
                int l = base_l + tid;
                out_mask[out_base + l] = (l < area) ? 0.0f : 1.0f;
            }
        }
    }
}

extern "C" void kernel_launch(void* const* d_in, const int* in_sizes, int n_in,
                              void* d_out, int out_size, void* d_ws, size_t ws_size,
                              hipStream_t stream) {
    const float* spatial = (const float*)d_in[0];   // [B, HW*T, D] fp32
    const float* bboxes  = (const float*)d_in[1];   // [B, N, 4] fp32

    ushort4* sp = (ushort4*)d_ws;                   // [B, HW, D] bf16 (3,538,944 B)
    const size_t SP_BYTES = (size_t)BATCH * HW * DIM * 2;   // 128B-aligned
    unsigned* barrier_cnt  = (unsigned*)((char*)d_ws + SP_BYTES);
    unsigned* barrier_flag = (unsigned*)((char*)d_ws + SP_BYTES + 128);

    float* out_feat = (float*)d_out;                               // [B,N,L,D]
    float* out_mask = (float*)d_out + (size_t)BATCH * NBOX * ROI_L * DIM;  // [B,N,L]

    // zero the barrier state each call (graph-capturable async memset)
    hipMemsetAsync((char*)d_ws + SP_BYTES, 0, 256, stream);

    fused_roi_kernel<<<GRID, 192, 0, stream>>>(spatial, bboxes, sp, barrier_cnt,
                                               barrier_flag, out_feat, out_mask);
}

// Round 11
// 79.064 us; speedup vs baseline: 4.5656x; 4.5656x over previous
//
#include <hip/hip_runtime.h>

// Static config (matches reference)
#define HP 24
#define WP 24
#define TF 9
#define HW (HP * WP)        // 576
#define DIM 768
#define D4 (DIM / 4)        // 192 groups of 4 elements per row
#define BATCH 4
#define NBOX 50
#define ROI_L (HP * WP)     // 576
#define ROWS_PB 2           // rows per gather block (R7=4, R8=8; probing 2)
#define LGROUPS (ROI_L / ROWS_PB)  // 288

typedef float v4f __attribute__((ext_vector_type(4)));

// fp32 -> bf16 round-to-nearest-even (no NaN inputs in this problem)
__device__ __forceinline__ unsigned short f2bf(float f) {
    unsigned u = __float_as_uint(f);
    unsigned rounding = 0x7FFFu + ((u >> 16) & 1u);
    return (unsigned short)((u + rounding) >> 16);
}

// ---------------------------------------------------------------------------
// Kernel 1: temporal mean  [B, HW*T, D] -> sp (bf16) [B, HW, D]
// (identical to R5/R7)
// ---------------------------------------------------------------------------
__global__ void __launch_bounds__(256)
temporal_mean_kernel(const float* __restrict__ in, ushort4* __restrict__ sp) {
    int i = blockIdx.x * blockDim.x + threadIdx.x;
    const int total = BATCH * HW * D4;
    if (i >= total) return;
    int d4 = i % D4;
    int rest = i / D4;
    int hw = rest % HW;
    int b = rest / HW;

    const float4* src =
        (const float4*)(in + ((size_t)(b * HW * TF + hw * TF)) * DIM) + d4;
    float4 acc = make_float4(0.f, 0.f, 0.f, 0.f);
#pragma unroll
    for (int t = 0; t < TF; ++t) {
        float4 v = src[(size_t)t * D4];
        acc.x += v.x; acc.y += v.y; acc.z += v.z; acc.w += v.w;
    }
    acc.x /= 9.0f; acc.y /= 9.0f; acc.z /= 9.0f; acc.w /= 9.0f;

    ushort4 o;
    o.x = f2bf(acc.x); o.y = f2bf(acc.y); o.z = f2bf(acc.z); o.w = f2bf(acc.w);
    sp[i] = o;
}

// ---------------------------------------------------------------------------
// Kernel 2: ROI gather + mask. Identical dataflow/cache policy to R7
// (bf16 sp reads cached, out_feat NT stores, mask cached) — only change:
// 2 rows per block (57600 blocks) instead of 4 (28800). More co-resident
// independent load->store chains per CU; each block still writes one dense
// contiguous 8KB segment in block order.
// ---------------------------------------------------------------------------
__global__ void __launch_bounds__(192)
roi_gather_kernel(const ushort4* __restrict__ sp, const float* __restrict__ bboxes,
                  float* __restrict__ out_feat, float* __restrict__ out_mask) {
    int bid = blockIdx.x;           // [0, B*N*LGROUPS)
    int lg = bid % LGROUPS;
    int rest = bid / LGROUPS;
    int n = rest % NBOX;
    int b = rest / NBOX;
    int tid = threadIdx.x;          // 0..191

    float4 bb = ((const float4*)bboxes)[b * NBOX + n];
    float cx = bb.x, cy = bb.y, bw = bb.z, bh = bb.w;
    float bwp = bw * 1.2f;
    float bhp = bh * 1.2f;

    // astype(int32) truncates toward zero == C (int) cast
    int col_start = max((int)((cx - bwp * 0.5f) * (float)WP), 0);
    int col_end   = min((int)((cx + bwp * 0.5f) * (float)WP), WP);
    int row_start = max((int)((cy - bhp * 0.5f) * (float)HP), 0);
    int row_end   = min((int)((cy + bhp * 0.5f) * (float)HP), HP);

    // (a+b)/2 then trunc; a,b >= 0 so >>1 is exact
    int col_mid = (col_start + col_end) >> 1;
    int row_mid = (row_start + row_end) >> 1;
    // half_min = MIN_PATCHES/2 = 1
    col_start = min(col_start, max(col_mid - 1, 0));
    col_end   = max(col_end,   min(col_mid + 2, WP));
    row_start = min(row_start, max(row_mid - 1, 0));
    row_end   = max(row_end,   min(row_mid + 2, HP));

    int h = max(row_end - row_start, 0);
    int w = max(col_end - col_start, 0);
    int area = h * w;
    int wsafe = max(w, 1);

    int base_l = lg * ROWS_PB;
    size_t out_base = (size_t)(b * NBOX + n) * ROI_L;  // in rows
    v4f* outf4 = (v4f*)out_feat;

#pragma unroll
    for (int s = 0; s < ROWS_PB; ++s) {
        int l = base_l + s;
        bool valid = l < area;
        v4f v = (v4f)(0.f);
        if (valid) {
            int r = row_start + l / wsafe;
            int c = col_start + l % wsafe;
            // valid => r,c in [0,23]; reference clip is a no-op here.
            ushort4 u = sp[(size_t)(b * HW + r * WP + c) * D4 + tid];
            // bf16 -> fp32 is an exact bit shift
            v.x = __uint_as_float((unsigned)u.x << 16);
            v.y = __uint_as_float((unsigned)u.y << 16);
            v.z = __uint_as_float((unsigned)u.z << 16);
            v.w = __uint_as_float((unsigned)u.w << 16);
        }
        __builtin_nontemporal_store(v, &outf4[(out_base + l) * D4 + tid]);
    }

    // Mask: lanes 0..1 write one contiguous 8B segment
    if (tid < ROWS_PB) {
        int l = base_l + tid;
        out_mask[out_base + l] = (l < area) ? 0.0f : 1.0f;  // True(=1) = padding
    }
}

extern "C" void kernel_launch(void* const* d_in, const int* in_sizes, int n_in,
                              void* d_out, int out_size, void* d_ws, size_t ws_size,
                              hipStream_t stream) {
    const float* spatial = (const float*)d_in[0];   // [B, HW*T, D] fp32
    const float* bboxes  = (const float*)d_in[1];   // [B, N, 4] fp32

    ushort4* sp = (ushort4*)d_ws;                   // [B, HW, D] bf16 (3.5 MB)

    float* out_feat = (float*)d_out;                               // [B,N,L,D]
    float* out_mask = (float*)d_out + (size_t)BATCH * NBOX * ROI_L * DIM;  // [B,N,L]

    {
        int total = BATCH * HW * D4;            // 442368
        int block = 256;
        int grid = (total + block - 1) / block; // 1728
        temporal_mean_kernel<<<grid, block, 0, stream>>>(spatial, sp);
    }
    {
        int grid = BATCH * NBOX * LGROUPS;      // 57600
        roi_gather_kernel<<<grid, 192, 0, stream>>>(sp, bboxes, out_feat, out_mask);
    }
}